// Round 9
// baseline (86.736 us; speedup 1.0000x reference)
//
#include <hip/hip_runtime.h>
#include <hip/hip_fp16.h>
#include <cmath>

// Radon backprojection, two-phase: pack (fp16 pair table, zero-padded) +
// single fused gather kernel (no partials, no reduce, no barriers).
//
// R7 post-mortem: barrier removal won -6.3 us; remaining ~29 us of ours is
// VALU-issue in the gather loop (~27 instr/pixel-angle), the 9 MB
// partial+reduce round trip, and 2 launch gaps. R8/R9:
//  (a) table entry j <-> i0=j-1, borders zero -> no validity mask math
//  (b) v_dot2_f32_f16: one instr per batch lerp (replaces 2 cvt + 2 fma)
//  (c) one kernel over all angles writing out directly (issue-bound work is
//      occupancy-invariant; unroll-4 ILP hides gather latency)
// R9 fix: clang's cvt_pkrtz/fdot2 use __fp16 ext_vector, not _Float16.

typedef __fp16 half2v __attribute__((ext_vector_type(2)));

__device__ __forceinline__ half2v as_h2(unsigned u) {
    union { unsigned u; half2v h; } x; x.u = u; return x.h;
}

__global__ __launch_bounds__(256) void radon_pack(
    const float* __restrict__ sino,
    const float* __restrict__ thetas,
    const float* __restrict__ positions,
    uint4* __restrict__ packed,        // [A][PES]; entry j: (v[j-1], v[j]) x4 batches
    float2* __restrict__ trig,         // [A+1]; trig[A].x = q0
    int A, int P, int PES, int bstride)
{
    const int idx = blockIdx.x * 256 + threadIdx.x;
    const int a = idx / PES;
    const int j = idx - a * PES;
    if (a >= A) return;

    const float p0     = positions[0];
    const float inv_dp = 1.0f / (positions[1] - p0);
    if (j == 0) {
        float th = thetas[a];
        trig[a] = make_float2(cosf(th) * inv_dp, sinf(th) * inv_dp);
        if (a == 0) trig[A] = make_float2(-p0 * inv_dp, 0.0f);
    }

    uint4 e = make_uint4(0, 0, 0, 0);
    if (j >= 1 && j <= P - 1) {
        const float* s = sino + (size_t)a * P;
        unsigned* ep = (unsigned*)&e;
#pragma unroll
        for (int b = 0; b < 4; ++b) {
            const float* sb = s + (size_t)b * bstride;
            __half2 h = __floats2half2_rn(sb[j - 1], sb[j]);  // lo=v0, hi=v1
            ep[b] = *(const unsigned*)&h;
        }
    }
    packed[(size_t)a * PES + j] = e;
}

__global__ __launch_bounds__(256) void radon_gather(
    const uint4* __restrict__ packed,  // [A][PES]
    const float2* __restrict__ trig,   // [A+1]
    float* __restrict__ out,           // [4][nn]
    int A, int P, int PES, int N)
{
    const int tid = threadIdx.x;
    const int nn  = N * N;
    const int pix = blockIdx.x * 256 + tid;

    const int x = pix % N;
    const int y = pix / N;
    const float half = (float)(N - 1) * 0.5f;
    const float cx = (float)x - half;
    const float cy = half - (float)y;
    const float q0 = trig[A].x;        // uniform -> s_load

    float acc0 = 0.f, acc1 = 0.f, acc2 = 0.f, acc3 = 0.f;

#pragma unroll 4
    for (int a = 0; a < A; ++a) {
        float2 t  = trig[a];           // uniform -> s_load_dwordx2
        float f   = fmaf(cx, t.x, fmaf(cy, t.y, q0));
        float i0f = floorf(f);
        float w   = f - i0f;
        int   i0  = (int)i0f;
        int   j   = min(max(i0, -1), P - 1) + 1;   // borders -> zero entries

        half2v w2 = __builtin_amdgcn_cvt_pkrtz(1.0f - w, w);   // (om, wm)
        uint4 e = packed[(size_t)a * PES + j];      // global_load_dwordx4
        acc0 = __builtin_amdgcn_fdot2(as_h2(e.x), w2, acc0, false);
        acc1 = __builtin_amdgcn_fdot2(as_h2(e.y), w2, acc1, false);
        acc2 = __builtin_amdgcn_fdot2(as_h2(e.z), w2, acc2, false);
        acc3 = __builtin_amdgcn_fdot2(as_h2(e.w), w2, acc3, false);
    }

    if (pix < nn) {
        float* op = out + pix;
        op[0]              = acc0;
        op[(size_t)nn]     = acc1;
        op[(size_t)2 * nn] = acc2;
        op[(size_t)3 * nn] = acc3;
    }
}

// Generic fallback: direct per-batch kernel (any shape).
__global__ __launch_bounds__(256) void radon_direct_kernel(
    const float* __restrict__ sino,
    const float* __restrict__ thetas,
    const float* __restrict__ positions,
    float* __restrict__ out,
    int A, int P, int N, int BC)
{
    const int nn  = N * N;
    const int pix = blockIdx.x * blockDim.x + threadIdx.x;
    if (pix >= nn) return;
    const float p0     = positions[0];
    const float inv_dp = 1.0f / (positions[1] - p0);
    const int x = pix % N;
    const int y = pix / N;
    const float half = (float)(N - 1) * 0.5f;
    const float cx = (float)x - half;
    const float cy = half - (float)y;
    for (int b = 0; b < BC; ++b) {
        float acc = 0.0f;
        for (int a = 0; a < A; ++a) {
            float th = thetas[a];
            float f  = (cx * cosf(th) + cy * sinf(th) - p0) * inv_dp;
            float i0f = floorf(f);
            int i0 = (int)i0f;
            float w = f - i0f;
            float m = (i0 >= 0 && i0 <= P - 2) ? 1.0f : 0.0f;
            int ic = min(max(i0, 0), P - 2);
            const float* row = sino + ((size_t)b * A + a) * P + ic;
            acc = fmaf(m, fmaf(w, row[1] - row[0], row[0]), acc);
        }
        out[(size_t)b * nn + pix] = acc;
    }
}

extern "C" void kernel_launch(void* const* d_in, const int* in_sizes, int n_in,
                              void* d_out, int out_size, void* d_ws, size_t ws_size,
                              hipStream_t stream) {
    const float* sino      = (const float*)d_in[0];
    const float* thetas    = (const float*)d_in[1];
    const float* positions = (const float*)d_in[2];
    float* out             = (float*)d_out;

    const int A  = in_sizes[1];               // 180
    const int P  = in_sizes[2];               // 384
    const int BC = in_sizes[0] / (A * P);     // B*C = 4
    const int N  = (int)lroundf(sqrtf((float)(out_size / BC)));
    const int nn = N * N;
    const int bstride = A * P;

    const int PES = (P + 2 + 63) & ~63;       // padded entries per angle

    const size_t packed_bytes = (size_t)A * PES * sizeof(uint4);
    const size_t trig_bytes   = (size_t)(A + 1) * sizeof(float2);
    const size_t need = packed_bytes + trig_bytes;

    const bool fast = (BC == 4) && (A <= 1024) && (P >= 2)
                   && ((nn & 255) == 0) && (ws_size >= need);

    if (fast) {
        uint4*  packed = (uint4*)d_ws;
        float2* trig   = (float2*)((char*)d_ws + packed_bytes);

        dim3 block(256);
        dim3 gpack(((unsigned)(A * PES) + 255) / 256);
        radon_pack<<<gpack, block, 0, stream>>>(
            sino, thetas, positions, packed, trig, A, P, PES, bstride);

        dim3 ggat(nn / 256);
        radon_gather<<<ggat, block, 0, stream>>>(
            packed, trig, out, A, P, PES, N);
    } else {
        dim3 block(256);
        dim3 grid((nn + 255) / 256);
        radon_direct_kernel<<<grid, block, 0, stream>>>(
            sino, thetas, positions, out, A, P, N, BC);
    }
}

// Round 10
// 75.627 us; speedup vs baseline: 1.1469x; 1.1469x over previous
//
#include <hip/hip_runtime.h>
#include <hip/hip_fp16.h>
#include <cmath>

// Radon backprojection, three-phase: pack (zero-padded fp16 pair table) +
// chunked partial gather (fdot2 inner loop, no barriers) + reduce.
//
// R9 post-mortem: single fused gather = 4 waves/CU = latency-bound (~30 us).
// Wave count is fixed by nn; only angle-chunking raises occupancy. R10 =
// R7 structure (ACHUNKS=8 -> 32 waves/CU) + R9 inner loop (1 dwordx4 gather
// + cvt_pkrtz + 4x fdot2 per pixel-angle, no validity mask thanks to the
// zero-padded table).

#define ACHUNKS 8

typedef __fp16 half2v __attribute__((ext_vector_type(2)));

__device__ __forceinline__ half2v as_h2(unsigned u) {
    union { unsigned u; half2v h; } x; x.u = u; return x.h;
}

__global__ __launch_bounds__(256) void radon_pack(
    const float* __restrict__ sino,
    const float* __restrict__ thetas,
    const float* __restrict__ positions,
    uint4* __restrict__ packed,        // [A][PES]; entry j: (v[j-1], v[j]) x4 batches
    float2* __restrict__ trig,         // [A+1]; trig[A].x = q0
    int A, int P, int PES, int bstride)
{
    const int idx = blockIdx.x * 256 + threadIdx.x;
    const int a = idx / PES;
    const int j = idx - a * PES;
    if (a >= A) return;

    const float p0     = positions[0];
    const float inv_dp = 1.0f / (positions[1] - p0);
    if (j == 0) {
        float th = thetas[a];
        trig[a] = make_float2(cosf(th) * inv_dp, sinf(th) * inv_dp);
        if (a == 0) trig[A] = make_float2(-p0 * inv_dp, 0.0f);
    }

    uint4 e = make_uint4(0, 0, 0, 0);
    if (j >= 1 && j <= P - 1) {
        const float* s = sino + (size_t)a * P;
        unsigned* ep = (unsigned*)&e;
#pragma unroll
        for (int b = 0; b < 4; ++b) {
            const float* sb = s + (size_t)b * bstride;
            __half2 h = __floats2half2_rn(sb[j - 1], sb[j]);  // lo=v0, hi=v1
            ep[b] = *(const unsigned*)&h;
        }
    }
    packed[(size_t)a * PES + j] = e;
}

__global__ __launch_bounds__(256) void radon_partial_pk(
    const uint4* __restrict__ packed,  // [A][PES]
    const float2* __restrict__ trig,   // [A+1]
    float* __restrict__ part,          // [ACHUNKS][4][nn]
    int A, int P, int PES, int N, int chunk)
{
    const int tid = threadIdx.x;
    const int nn  = N * N;
    const int pix = blockIdx.x * 256 + tid;
    const int a0  = blockIdx.y * chunk;
    const int a1  = min(A, a0 + chunk);

    const int x = pix % N;
    const int y = pix / N;
    const float half = (float)(N - 1) * 0.5f;
    const float cx = (float)x - half;
    const float cy = half - (float)y;
    const float q0 = trig[A].x;        // uniform -> s_load

    float acc0 = 0.f, acc1 = 0.f, acc2 = 0.f, acc3 = 0.f;

#pragma unroll 4
    for (int a = a0; a < a1; ++a) {
        float2 t  = trig[a];           // uniform -> s_load_dwordx2
        float f   = fmaf(cx, t.x, fmaf(cy, t.y, q0));
        float i0f = floorf(f);
        float w   = f - i0f;
        int   i0  = (int)i0f;
        int   j   = min(max(i0, -1), P - 1) + 1;   // borders -> zero entries

        half2v w2 = __builtin_amdgcn_cvt_pkrtz(1.0f - w, w);   // (om, wm)
        uint4 e = packed[(size_t)a * PES + j];      // global_load_dwordx4
        acc0 = __builtin_amdgcn_fdot2(as_h2(e.x), w2, acc0, false);
        acc1 = __builtin_amdgcn_fdot2(as_h2(e.y), w2, acc1, false);
        acc2 = __builtin_amdgcn_fdot2(as_h2(e.z), w2, acc2, false);
        acc3 = __builtin_amdgcn_fdot2(as_h2(e.w), w2, acc3, false);
    }

    if (pix < nn) {
        float* pp = part + (size_t)blockIdx.y * 4 * nn + pix;
        pp[0]              = acc0;
        pp[(size_t)nn]     = acc1;
        pp[(size_t)2 * nn] = acc2;
        pp[(size_t)3 * nn] = acc3;
    }
}

__global__ __launch_bounds__(256) void radon_reduce_kernel(
    const float4* __restrict__ part,   // [nchunks][BN4] in float4
    float4* __restrict__ out,
    int BN4, int nchunks)
{
    int i = blockIdx.x * blockDim.x + threadIdx.x;
    if (i >= BN4) return;
    float4 s = make_float4(0.f, 0.f, 0.f, 0.f);
    for (int c = 0; c < nchunks; ++c) {
        float4 v = part[(size_t)c * BN4 + i];
        s.x += v.x; s.y += v.y; s.z += v.z; s.w += v.w;
    }
    out[i] = s;
}

// Generic fallback: direct per-batch kernel (any shape).
__global__ __launch_bounds__(256) void radon_direct_kernel(
    const float* __restrict__ sino,
    const float* __restrict__ thetas,
    const float* __restrict__ positions,
    float* __restrict__ out,
    int A, int P, int N, int BC)
{
    const int nn  = N * N;
    const int pix = blockIdx.x * blockDim.x + threadIdx.x;
    if (pix >= nn) return;
    const float p0     = positions[0];
    const float inv_dp = 1.0f / (positions[1] - p0);
    const int x = pix % N;
    const int y = pix / N;
    const float half = (float)(N - 1) * 0.5f;
    const float cx = (float)x - half;
    const float cy = half - (float)y;
    for (int b = 0; b < BC; ++b) {
        float acc = 0.0f;
        for (int a = 0; a < A; ++a) {
            float th = thetas[a];
            float f  = (cx * cosf(th) + cy * sinf(th) - p0) * inv_dp;
            float i0f = floorf(f);
            int i0 = (int)i0f;
            float w = f - i0f;
            float m = (i0 >= 0 && i0 <= P - 2) ? 1.0f : 0.0f;
            int ic = min(max(i0, 0), P - 2);
            const float* row = sino + ((size_t)b * A + a) * P + ic;
            acc = fmaf(m, fmaf(w, row[1] - row[0], row[0]), acc);
        }
        out[(size_t)b * nn + pix] = acc;
    }
}

extern "C" void kernel_launch(void* const* d_in, const int* in_sizes, int n_in,
                              void* d_out, int out_size, void* d_ws, size_t ws_size,
                              hipStream_t stream) {
    const float* sino      = (const float*)d_in[0];
    const float* thetas    = (const float*)d_in[1];
    const float* positions = (const float*)d_in[2];
    float* out             = (float*)d_out;

    const int A  = in_sizes[1];               // 180
    const int P  = in_sizes[2];               // 384
    const int BC = in_sizes[0] / (A * P);     // B*C = 4
    const int N  = (int)lroundf(sqrtf((float)(out_size / BC)));
    const int nn = N * N;
    const int bstride = A * P;

    const int PES   = (P + 2 + 63) & ~63;     // padded entries per angle
    const int chunk = (A + ACHUNKS - 1) / ACHUNKS;

    const size_t part_bytes   = (size_t)ACHUNKS * 4 * nn * sizeof(float);
    const size_t packed_bytes = (size_t)A * PES * sizeof(uint4);
    const size_t trig_bytes   = (size_t)(A + 1) * sizeof(float2);
    const size_t need = part_bytes + packed_bytes + trig_bytes;

    const bool fast = (BC == 4) && (A <= 1024) && (P >= 2)
                   && ((nn & 255) == 0) && ((nn & 3) == 0) && (ws_size >= need);

    if (fast) {
        float*  part   = (float*)d_ws;
        uint4*  packed = (uint4*)((char*)d_ws + part_bytes);
        float2* trig   = (float2*)((char*)d_ws + part_bytes + packed_bytes);

        dim3 block(256);
        dim3 gpack(((unsigned)(A * PES) + 255) / 256);
        radon_pack<<<gpack, block, 0, stream>>>(
            sino, thetas, positions, packed, trig, A, P, PES, bstride);

        dim3 gpart(nn / 256, ACHUNKS);
        radon_partial_pk<<<gpart, block, 0, stream>>>(
            packed, trig, part, A, P, PES, N, chunk);

        const int BN4 = nn;                   // 4*nn/4
        dim3 gred((BN4 + 255) / 256);
        radon_reduce_kernel<<<gred, block, 0, stream>>>(
            (const float4*)part, (float4*)out, BN4, ACHUNKS);
    } else {
        dim3 block(256);
        dim3 grid((nn + 255) / 256);
        radon_direct_kernel<<<grid, block, 0, stream>>>(
            sino, thetas, positions, out, A, P, N, BC);
    }
}